// Round 4
// baseline (28731.033 us; speedup 1.0000x reference)
//
#include <hip/hip_runtime.h>
#include <hip/hip_bf16.h>

// GRU forward, B=64 S=512 I=512 H=1024. fp32 I/O, bf16 MFMA internals.
// Round 4: persistent kernel, 64 WGs x 256 thr. Flag barriers with NO cache
// maintenance (round-3 killer: agent release/acquire = wbl2/inv L2 sweeps,
// ~27 us/step). All cross-WG data via relaxed agent atomics (sc1, MALL-
// coherent); weights/x via normal cached loads (L2 never invalidated).
// Phase 1: each WG computes z AND r for its 16 cols (shared A-fragments).
// Phase 2: h_hat + h update. 4-way K-split per WG, LDS reduce.

#define B_ 64
#define S_ 512
#define I_ 512
#define H_ 1024
#define NWG 64
#define FSTRIDE 32  // ints between flags (128 B)

typedef short short8 __attribute__((ext_vector_type(8)));
typedef float floatx4 __attribute__((ext_vector_type(4)));

__device__ inline floatx4 mfma16(short8 a, short8 b, floatx4 c) {
    return __builtin_amdgcn_mfma_f32_16x16x32_bf16(a, b, c, 0, 0, 0);
}

__device__ inline short f2bf(float f) {
    union { float f; unsigned u; } v; v.f = f;
    unsigned r = (v.u + 0x7FFFu + ((v.u >> 16) & 1u)) >> 16;
    return (short)r;
}

__device__ inline short8 ld8(const short* p) {
    return *reinterpret_cast<const short8*>(p);
}

__device__ inline short8 loadA_f32(const float* p) {
    const float4* q = reinterpret_cast<const float4*>(p);
    float4 f0 = q[0], f1 = q[1];
    short8 a;
    a[0] = f2bf(f0.x); a[1] = f2bf(f0.y); a[2] = f2bf(f0.z); a[3] = f2bf(f0.w);
    a[4] = f2bf(f1.x); a[5] = f2bf(f1.y); a[6] = f2bf(f1.z); a[7] = f2bf(f1.w);
    return a;
}

// ---- agent-coherent (sc1) accessors: relaxed atomics, no wbl2/inv ----
__device__ inline float ldc_f(const float* p) {
    return __hip_atomic_load(p, __ATOMIC_RELAXED, __HIP_MEMORY_SCOPE_AGENT);
}
__device__ inline void stc_f(float* p, float v) {
    __hip_atomic_store(p, v, __ATOMIC_RELAXED, __HIP_MEMORY_SCOPE_AGENT);
}
__device__ inline void stc_s(short* p, short v) {
    __hip_atomic_store(p, v, __ATOMIC_RELAXED, __HIP_MEMORY_SCOPE_AGENT);
}
__device__ inline short8 ldc8(const short* p) {
    const int* q = reinterpret_cast<const int*>(p);
    union { int i[4]; short8 s; } u;
    u.i[0] = __hip_atomic_load(q + 0, __ATOMIC_RELAXED, __HIP_MEMORY_SCOPE_AGENT);
    u.i[1] = __hip_atomic_load(q + 1, __ATOMIC_RELAXED, __HIP_MEMORY_SCOPE_AGENT);
    u.i[2] = __hip_atomic_load(q + 2, __ATOMIC_RELAXED, __HIP_MEMORY_SCOPE_AGENT);
    u.i[3] = __hip_atomic_load(q + 3, __ATOMIC_RELAXED, __HIP_MEMORY_SCOPE_AGENT);
    return u.s;
}

// ---- bulk fp32 -> bf16 ----
__global__ __launch_bounds__(256) void cvt8k(const float* __restrict__ src,
                                             short* __restrict__ dst, int n8) {
    int i = blockIdx.x * 256 + threadIdx.x;
    if (i >= n8) return;
    const float4* p = reinterpret_cast<const float4*>(src) + (size_t)i * 2;
    float4 f0 = p[0], f1 = p[1];
    short8 o;
    o[0] = f2bf(f0.x); o[1] = f2bf(f0.y); o[2] = f2bf(f0.z); o[3] = f2bf(f0.w);
    o[4] = f2bf(f1.x); o[5] = f2bf(f1.y); o[6] = f2bf(f1.z); o[7] = f2bf(f1.w);
    reinterpret_cast<short8*>(dst)[i] = o;
}

// ---- init h state + zero flags ----
__global__ __launch_bounds__(256) void gru_init(const float* __restrict__ h0,
                                                float* __restrict__ h_f32,
                                                short* __restrict__ h_bf16,
                                                int* __restrict__ flags) {
    int i = blockIdx.x * 256 + threadIdx.x;
    if (i < B_ * H_) {
        float v = h0[i];
        h_f32[i] = v;
        h_bf16[i] = f2bf(v);
    }
    if (i < NWG * FSTRIDE) flags[i] = 0;
}

// Barrier: syncthreads drains vmcnt for every wave (compiler-guaranteed),
// so all sc1 stores are MALL-visible before the flag store. No fences.
__device__ inline void gbar(int* flags, int ep) {
    asm volatile("s_waitcnt vmcnt(0)" ::: "memory");  // insurance; usually free
    __syncthreads();
    if (threadIdx.x == 0)
        __hip_atomic_store(flags + (size_t)blockIdx.x * FSTRIDE, ep,
                           __ATOMIC_RELAXED, __HIP_MEMORY_SCOPE_AGENT);
    if (threadIdx.x < NWG) {
        while (__hip_atomic_load(flags + (size_t)threadIdx.x * FSTRIDE,
                                 __ATOMIC_RELAXED, __HIP_MEMORY_SCOPE_AGENT) < ep)
            __builtin_amdgcn_s_sleep(1);
    }
    __syncthreads();
    asm volatile("" ::: "memory");
}

// MFMA 16x16x32 bf16 NT (m89/m91-verified): D col(lane&15)=W-row j,
// row(quad*4+reg)=batch b. K layout: [0,512)=x@W part, [512,1536)=h/rh@U part.
template <int MODE>  // 0: x fp32 on-the-fly cvt, 1: xb bf16 precomputed
__global__ __launch_bounds__(256) void gru_persist(
    const float* __restrict__ x, const short* __restrict__ xb,
    const short* __restrict__ Wzb, const short* __restrict__ Wrb, const short* __restrict__ Whb,
    const short* __restrict__ Uzb, const short* __restrict__ Urb, const short* __restrict__ Uhb,
    const float* __restrict__ bz, const float* __restrict__ br, const float* __restrict__ bh,
    float* __restrict__ h_f32, short* __restrict__ h_b,
    float* __restrict__ z_f32, short* __restrict__ rh,
    int* __restrict__ flags, float* __restrict__ out)
{
    __shared__ floatx4 red[4 * 8 * 64];  // 32 KB: [wave][accset][lane]

    int wg = blockIdx.x;
    int tid = threadIdx.x;
    int wave = tid >> 6, lane = tid & 63;
    int m16 = lane & 15, quad = lane >> 4;
    int jcol = wg * 16 + m16;            // this WG's output column for this lane
    int koff = quad * 8;

    const short* wzp = Wzb + (size_t)jcol * I_;
    const short* wrp = Wrb + (size_t)jcol * I_;
    const short* whp = Whb + (size_t)jcol * I_;
    const short* uzp = Uzb + (size_t)jcol * H_;
    const short* urp = Urb + (size_t)jcol * H_;
    const short* uhp = Uhb + (size_t)jcol * H_;

    int kstart = wave * 384;
    int nx = kstart >= 512 ? 0 : ((512 - kstart) >> 5);
    if (nx > 12) nx = 12;

    for (int t = 0; t < S_; ++t) {
        // ======== phase 1: z and r (shared A-fragments) ========
        {
            floatx4 az[4], ar[4];
#pragma unroll
            for (int bg = 0; bg < 4; ++bg) {
                az[bg] = floatx4{0.f, 0.f, 0.f, 0.f};
                ar[bg] = floatx4{0.f, 0.f, 0.f, 0.f};
            }
            for (int s = 0; s < nx; ++s) {           // x @ W part (cached loads)
                int k = kstart + s * 32 + koff;
                short8 bz8 = ld8(wzp + k);
                short8 br8 = ld8(wrp + k);
#pragma unroll
                for (int bg = 0; bg < 4; ++bg) {
                    int b = bg * 16 + m16;
                    short8 a8 = MODE ? ld8(xb + ((size_t)b * S_ + t) * I_ + k)
                                     : loadA_f32(x + ((size_t)b * S_ + t) * I_ + k);
                    az[bg] = mfma16(a8, bz8, az[bg]);
                    ar[bg] = mfma16(a8, br8, ar[bg]);
                }
            }
            for (int s = nx; s < 12; ++s) {          // h @ U part (coherent loads)
                int k = kstart + s * 32 - 512 + koff;
                short8 bz8 = ld8(uzp + k);
                short8 br8 = ld8(urp + k);
#pragma unroll
                for (int bg = 0; bg < 4; ++bg) {
                    short8 a8 = ldc8(h_b + (size_t)(bg * 16 + m16) * H_ + k);
                    az[bg] = mfma16(a8, bz8, az[bg]);
                    ar[bg] = mfma16(a8, br8, ar[bg]);
                }
            }
#pragma unroll
            for (int bg = 0; bg < 4; ++bg) {
                red[(wave * 8 + bg) * 64 + lane] = az[bg];
                red[(wave * 8 + 4 + bg) * 64 + lane] = ar[bg];
            }
            __syncthreads();
            if (wave < 2) {                           // wave0: z, wave1: r
                int sel = wave * 4;
                float bv = wave ? br[jcol] : bz[jcol];
#pragma unroll
                for (int bg = 0; bg < 4; ++bg) {
                    floatx4 a = red[(0 * 8 + sel + bg) * 64 + lane];
                    a += red[(1 * 8 + sel + bg) * 64 + lane];
                    a += red[(2 * 8 + sel + bg) * 64 + lane];
                    a += red[(3 * 8 + sel + bg) * 64 + lane];
#pragma unroll
                    for (int r = 0; r < 4; ++r) {
                        int b = bg * 16 + quad * 4 + r;
                        size_t idx = (size_t)b * H_ + jcol;
                        float sg = 1.0f / (1.0f + __expf(-(a[r] + bv)));
                        if (wave == 0) stc_f(z_f32 + idx, sg);
                        else           stc_s(rh + idx, f2bf(sg * ldc_f(h_f32 + idx)));
                    }
                }
            }
        }
        gbar(flags, 2 * t + 1);

        // ======== phase 2: h_hat + h update ========
        {
            floatx4 ah[4];
#pragma unroll
            for (int bg = 0; bg < 4; ++bg) ah[bg] = floatx4{0.f, 0.f, 0.f, 0.f};
            for (int s = 0; s < nx; ++s) {
                int k = kstart + s * 32 + koff;
                short8 b8 = ld8(whp + k);
#pragma unroll
                for (int bg = 0; bg < 4; ++bg) {
                    int b = bg * 16 + m16;
                    short8 a8 = MODE ? ld8(xb + ((size_t)b * S_ + t) * I_ + k)
                                     : loadA_f32(x + ((size_t)b * S_ + t) * I_ + k);
                    ah[bg] = mfma16(a8, b8, ah[bg]);
                }
            }
            for (int s = nx; s < 12; ++s) {
                int k = kstart + s * 32 - 512 + koff;
                short8 b8 = ld8(uhp + k);
#pragma unroll
                for (int bg = 0; bg < 4; ++bg) {
                    short8 a8 = ldc8(rh + (size_t)(bg * 16 + m16) * H_ + k);
                    ah[bg] = mfma16(a8, b8, ah[bg]);
                }
            }
#pragma unroll
            for (int bg = 0; bg < 4; ++bg)
                red[(wave * 4 + bg) * 64 + lane] = ah[bg];
            __syncthreads();
            if (wave == 0) {
                float bv = bh[jcol];
#pragma unroll
                for (int bg = 0; bg < 4; ++bg) {
                    floatx4 a = red[(0 * 4 + bg) * 64 + lane];
                    a += red[(1 * 4 + bg) * 64 + lane];
                    a += red[(2 * 4 + bg) * 64 + lane];
                    a += red[(3 * 4 + bg) * 64 + lane];
#pragma unroll
                    for (int r = 0; r < 4; ++r) {
                        int b = bg * 16 + quad * 4 + r;
                        size_t idx = (size_t)b * H_ + jcol;
                        float hh = tanhf(a[r] + bv);
                        float zz = ldc_f(z_f32 + idx);
                        float hv = ldc_f(h_f32 + idx);
                        float hn = fmaf(zz, hh - hv, hv);
                        stc_f(h_f32 + idx, hn);
                        stc_s(h_b + idx, f2bf(hn));
                        out[(size_t)b * S_ * H_ + (size_t)t * H_ + jcol] = hn;
                        if (t == S_ - 1) out[(size_t)B_ * S_ * H_ + idx] = hn;
                    }
                }
            }
        }
        gbar(flags, 2 * t + 2);
    }
}

extern "C" void kernel_launch(void* const* d_in, const int* in_sizes, int n_in,
                              void* d_out, int out_size, void* d_ws, size_t ws_size,
                              hipStream_t stream) {
    const float* x  = (const float*)d_in[0];
    const float* h0 = (const float*)d_in[1];
    const float* Wz = (const float*)d_in[2];
    const float* bz = (const float*)d_in[3];
    const float* Uz = (const float*)d_in[4];
    const float* Wr = (const float*)d_in[5];
    const float* br = (const float*)d_in[6];
    const float* Ur = (const float*)d_in[7];
    const float* Wh = (const float*)d_in[8];
    const float* bh = (const float*)d_in[9];
    const float* Uh = (const float*)d_in[10];
    float* out = (float*)d_out;

    const int HB = B_ * H_;
    const int WI = H_ * I_;
    const int UU = H_ * H_;
    const size_t XN = (size_t)B_ * S_ * I_;

    char* w = (char*)d_ws;
    float* h_f32 = (float*)w;  w += (size_t)HB * 4;
    float* z_f32 = (float*)w;  w += (size_t)HB * 4;
    short* h_b   = (short*)w;  w += (size_t)HB * 2;
    short* rh    = (short*)w;  w += (size_t)HB * 2;
    int*   flags = (int*)w;    w += (size_t)NWG * FSTRIDE * 4;
    short* Wzb   = (short*)w;  w += (size_t)WI * 2;
    short* Wrb   = (short*)w;  w += (size_t)WI * 2;
    short* Whb   = (short*)w;  w += (size_t)WI * 2;
    short* Uzb   = (short*)w;  w += (size_t)UU * 2;
    short* Urb   = (short*)w;  w += (size_t)UU * 2;
    short* Uhb   = (short*)w;  w += (size_t)UU * 2;
    size_t base_need = (size_t)(w - (char*)d_ws);
    bool XB = ws_size >= base_need + XN * 2;
    short* xb = (short*)w;

    gru_init<<<dim3(HB / 256), 256, 0, stream>>>(h0, h_f32, h_b, flags);
    cvt8k<<<dim3(WI / 8 / 256), 256, 0, stream>>>(Wz, Wzb, WI / 8);
    cvt8k<<<dim3(WI / 8 / 256), 256, 0, stream>>>(Wr, Wrb, WI / 8);
    cvt8k<<<dim3(WI / 8 / 256), 256, 0, stream>>>(Wh, Whb, WI / 8);
    cvt8k<<<dim3(UU / 8 / 256), 256, 0, stream>>>(Uz, Uzb, UU / 8);
    cvt8k<<<dim3(UU / 8 / 256), 256, 0, stream>>>(Ur, Urb, UU / 8);
    cvt8k<<<dim3(UU / 8 / 256), 256, 0, stream>>>(Uh, Uhb, UU / 8);
    if (XB) {
        cvt8k<<<dim3((int)(XN / 8 / 256)), 256, 0, stream>>>(x, xb, (int)(XN / 8));
        gru_persist<1><<<dim3(NWG), 256, 0, stream>>>(
            x, xb, Wzb, Wrb, Whb, Uzb, Urb, Uhb, bz, br, bh,
            h_f32, h_b, z_f32, rh, flags, out);
    } else {
        gru_persist<0><<<dim3(NWG), 256, 0, stream>>>(
            x, xb, Wzb, Wrb, Whb, Uzb, Urb, Uhb, bz, br, bh,
            h_f32, h_b, z_f32, rh, flags, out);
    }
}